// Round 1
// baseline (646.409 us; speedup 1.0000x reference)
//
#include <hip/hip_runtime.h>
#include <hip/hip_bf16.h>
#include <stdint.h>

// Problem constants
#define N_PATCH 3136     // 56*56 query rows
#define N_LIB   16384    // memory bank rows
#define DIM     768
#define IMGSZ   224
#define FM      56

typedef __bf16 bf16_t;
typedef __bf16 bf16x8 __attribute__((ext_vector_type(8)));
typedef float  f32x4  __attribute__((ext_vector_type(4)));

#define FLT_MAX_ 3.402823466e+38f

struct Scal {
  unsigned long long approx_max_pack;   // (bits(min_val)<<32) | (0xffffffff - row)
  unsigned long long cand_pack[64];     // per-candidate exact (bits(d2)<<32)|argmin_j
  int cand[64];
  int cand_count;
  int s_idx;
  float s_star;
  int mstar_idx;
};

__device__ __forceinline__ float wave_reduce_sum(float v) {
#pragma unroll
  for (int s = 32; s > 0; s >>= 1) v += __shfl_xor(v, s, 64);
  return v;
}

__device__ __forceinline__ unsigned long long shfl_xor_u64(unsigned long long v, int mask) {
  unsigned lo = (unsigned)v, hi = (unsigned)(v >> 32);
  lo = __shfl_xor(lo, mask, 64);
  hi = __shfl_xor(hi, mask, 64);
  return ((unsigned long long)hi << 32) | lo;
}

// ---------------------------------------------------------------- init
__global__ void init_kernel(unsigned long long* __restrict__ minpack, Scal* sc) {
  int i = blockIdx.x * 256 + threadIdx.x;
  if (i < N_PATCH) minpack[i] = ~0ULL;
  if (i < 64) sc->cand_pack[i] = ~0ULL;
  if (i == 0) {
    sc->approx_max_pack = 0ULL;
    sc->cand_count = 0;
    sc->s_idx = 0; sc->s_star = 0.f; sc->mstar_idx = 0;
  }
}

// ------------------------------------------------- prep: normalize + bf16 + norms
__global__ void prep_patch_kernel(const float* __restrict__ patch,
                                  const float* __restrict__ meanp,
                                  const float* __restrict__ stdp,
                                  bf16_t* __restrict__ pb, float* __restrict__ a2) {
  __shared__ float sbuf[4];
  int row = blockIdx.x;
  int t = threadIdx.x;
  float mu = meanp[0], sd = stdp[0];
  float acc = 0.f;
  for (int d = t; d < DIM; d += 256) {
    float v = (patch[(size_t)row * DIM + d] - mu) / sd;
    pb[(size_t)row * DIM + d] = (bf16_t)v;
    acc += v * v;
  }
  acc = wave_reduce_sum(acc);
  if ((t & 63) == 0) sbuf[t >> 6] = acc;
  __syncthreads();
  if (t == 0) a2[row] = sbuf[0] + sbuf[1] + sbuf[2] + sbuf[3];
}

__global__ void prep_lib_kernel(const float* __restrict__ lib,
                                bf16_t* __restrict__ lb, float* __restrict__ b2) {
  __shared__ float sbuf[4];
  int row = blockIdx.x;
  int t = threadIdx.x;
  float acc = 0.f;
  for (int d = t; d < DIM; d += 256) {
    float v = lib[(size_t)row * DIM + d];
    lb[(size_t)row * DIM + d] = (bf16_t)v;
    acc += v * v;
  }
  acc = wave_reduce_sum(acc);
  if ((t & 63) == 0) sbuf[t >> 6] = acc;
  __syncthreads();
  if (t == 0) b2[row] = sbuf[0] + sbuf[1] + sbuf[2] + sbuf[3];
}

// ------------------------------------------------- fused bf16 GEMM + row-min
// grid (25 M-tiles, 32 col-groups), block 256 = 4 waves.
// Each block: M-tile of 128 rows x 4 sequential N-tiles of 128 lib cols.
// Each wave: 64x64 = 4x4 MFMA tiles of 16x16x32 bf16.
#define BK 32
#define NT_PER_BLOCK 4

__global__ __launch_bounds__(256, 2)
void gemm_min_kernel(const bf16_t* __restrict__ pb, const bf16_t* __restrict__ lb,
                     const float* __restrict__ a2, const float* __restrict__ b2,
                     unsigned long long* __restrict__ minpack) {
  __shared__ __align__(16) bf16_t As[128 * BK];
  __shared__ __align__(16) bf16_t Bs[128 * BK];

  const int t = threadIdx.x;
  const int wave = t >> 6;
  const int lane = t & 63;
  const int l15 = lane & 15;
  const int quad = lane >> 4;            // 0..3
  const int wm = (wave >> 1) * 64;       // wave row offset within tile
  const int wn = (wave & 1) * 64;        // wave col offset within tile

  const int m0 = blockIdx.x * 128;
  const int n_base = blockIdx.y * (128 * NT_PER_BLOCK);

  // staging layout: thread t loads rows srow, srow+64 at 8-elem column chunk
  const int srow = t >> 2;               // 0..63
  const int scol = (t & 3) * 8;          // 0,8,16,24

  unsigned long long runmin[16];
#pragma unroll
  for (int i = 0; i < 16; i++) runmin[i] = ~0ULL;

  for (int nt = 0; nt < NT_PER_BLOCK; nt++) {
    const int n0 = n_base + nt * 128;

    f32x4 acc[4][4];
#pragma unroll
    for (int mi = 0; mi < 4; mi++)
#pragma unroll
      for (int ni = 0; ni < 4; ni++) {
        f32x4 z = {0.f, 0.f, 0.f, 0.f};
        acc[mi][ni] = z;
      }

    for (int k0 = 0; k0 < DIM; k0 += BK) {
      __syncthreads();   // previous iter's ds_reads done before overwrite
      {
        int gr0 = m0 + srow;       if (gr0 > N_PATCH - 1) gr0 = N_PATCH - 1;
        int gr1 = m0 + srow + 64;  if (gr1 > N_PATCH - 1) gr1 = N_PATCH - 1;
        uint4 va0 = *(const uint4*)(pb + (size_t)gr0 * DIM + k0 + scol);
        uint4 va1 = *(const uint4*)(pb + (size_t)gr1 * DIM + k0 + scol);
        uint4 vb0 = *(const uint4*)(lb + (size_t)(n0 + srow) * DIM + k0 + scol);
        uint4 vb1 = *(const uint4*)(lb + (size_t)(n0 + srow + 64) * DIM + k0 + scol);
        *(uint4*)(&As[srow * BK + scol]) = va0;
        *(uint4*)(&As[(srow + 64) * BK + scol]) = va1;
        *(uint4*)(&Bs[srow * BK + scol]) = vb0;
        *(uint4*)(&Bs[(srow + 64) * BK + scol]) = vb1;
      }
      __syncthreads();

      bf16x8 afr[4], bfr[4];
#pragma unroll
      for (int mi = 0; mi < 4; mi++)
        afr[mi] = *(const bf16x8*)(&As[(wm + mi * 16 + l15) * BK + quad * 8]);
#pragma unroll
      for (int ni = 0; ni < 4; ni++)
        bfr[ni] = *(const bf16x8*)(&Bs[(wn + ni * 16 + l15) * BK + quad * 8]);

#pragma unroll
      for (int mi = 0; mi < 4; mi++)
#pragma unroll
        for (int ni = 0; ni < 4; ni++)
          acc[mi][ni] = __builtin_amdgcn_mfma_f32_16x16x32_bf16(afr[mi], bfr[ni],
                                                                acc[mi][ni], 0, 0, 0);
    }

    // epilogue for this N-tile: d2 = a2 + b2 - 2*dot, packed min over columns
    float b2n[4];
#pragma unroll
    for (int ni = 0; ni < 4; ni++) b2n[ni] = b2[n0 + wn + ni * 16 + l15];

#pragma unroll
    for (int mi = 0; mi < 4; mi++) {
#pragma unroll
      for (int r = 0; r < 4; r++) {
        int mrow = m0 + wm + mi * 16 + quad * 4 + r;
        float a2v = a2[mrow < N_PATCH ? mrow : (N_PATCH - 1)];
        unsigned long long best = ~0ULL;
#pragma unroll
        for (int ni = 0; ni < 4; ni++) {
          // C/D layout: col = lane&15, row = quad*4 + reg  [m89/m91]
          float d2v = a2v + b2n[ni] - 2.0f * acc[mi][ni][r];
          d2v = fmaxf(d2v, 0.0f);
          unsigned n = (unsigned)(n0 + wn + ni * 16 + l15);
          unsigned long long pk = (((unsigned long long)__float_as_uint(d2v)) << 32) | n;
          if (pk < best) best = pk;
        }
        // butterfly min across 16 lanes sharing these rows
#pragma unroll
        for (int s = 1; s < 16; s <<= 1) {
          unsigned long long o = shfl_xor_u64(best, s);
          if (o < best) best = o;
        }
        if (best < runmin[mi * 4 + r]) runmin[mi * 4 + r] = best;
      }
    }
  }

  if (l15 == 0) {
#pragma unroll
    for (int mi = 0; mi < 4; mi++)
#pragma unroll
      for (int r = 0; r < 4; r++) {
        int mrow = m0 + wm + mi * 16 + quad * 4 + r;
        if (mrow < N_PATCH) atomicMin(&minpack[mrow], runmin[mi * 4 + r]);
      }
  }
}

// ------------------------------------------------- finalize rows + approx argmax
__global__ void finalize_kernel(const unsigned long long* __restrict__ minpack,
                                float* __restrict__ min_val, int* __restrict__ min_idx,
                                Scal* sc) {
  int i = blockIdx.x * 256 + threadIdx.x;
  if (i >= N_PATCH) return;
  unsigned long long p = minpack[i];
  float d2 = __uint_as_float((unsigned)(p >> 32));
  float v = sqrtf(d2);
  min_val[i] = v;
  min_idx[i] = (int)(p & 0xffffffffu);
  unsigned long long mp = (((unsigned long long)__float_as_uint(v)) << 32) |
                          (unsigned)(0xffffffffu - (unsigned)i);  // ties -> smaller row
  atomicMax(&sc->approx_max_pack, mp);
}

// ------------------------------------------------- collect argmax candidates
__global__ void collect_kernel(const float* __restrict__ min_val, Scal* sc) {
  int i = blockIdx.x * 256 + threadIdx.x;
  if (i >= N_PATCH) return;
  float amax = __uint_as_float((unsigned)(sc->approx_max_pack >> 32));
  if (min_val[i] >= amax - 0.02f) {   // >6 sigma of bf16 noise
    int p = atomicAdd(&sc->cand_count, 1);
    if (p < 64) sc->cand[p] = i;
  }
}

// ------------------------------------------------- exact fp32 refine of candidates
// grid (64 candidates, 32 lib chunks), block 256 = 4 waves, wave = 128 lib rows
__global__ void refine_kernel(const float* __restrict__ patch, const float* __restrict__ lib,
                              const float* __restrict__ meanp, const float* __restrict__ stdp,
                              Scal* sc) {
  int c = blockIdx.x;
  int cnt = sc->cand_count; if (cnt > 64) cnt = 64;
  if (c >= cnt) return;
  int row = sc->cand[c];
  int wave = threadIdx.x >> 6, lane = threadIdx.x & 63;
  float mu = meanp[0], sd = stdp[0];
  float pv[12];
#pragma unroll
  for (int k = 0; k < 12; k++)
    pv[k] = (patch[(size_t)row * DIM + lane + 64 * k] - mu) / sd;

  unsigned long long best = ~0ULL;
  for (int rr = 0; rr < 128; rr++) {
    int j = blockIdx.y * 512 + wave * 128 + rr;
    float acc = 0.f;
#pragma unroll
    for (int k = 0; k < 12; k++) {
      float diff = pv[k] - lib[(size_t)j * DIM + lane + 64 * k];
      acc += diff * diff;
    }
    acc = wave_reduce_sum(acc);
    unsigned long long pk = (((unsigned long long)__float_as_uint(acc)) << 32) | (unsigned)j;
    if (pk < best) best = pk;
  }
  if (lane == 0) atomicMin(&sc->cand_pack[c], best);
}

// ------------------------------------------------- pick exact argmax -> s_idx, s_star, m_star
__global__ void pick_kernel(Scal* sc) {
  if (threadIdx.x != 0) return;
  int cnt = sc->cand_count; if (cnt > 64) cnt = 64;
  float bestv = -1.f; int bestrow = 0x7fffffff; int bestms = 0;
  for (int c = 0; c < cnt; c++) {
    float v = sqrtf(__uint_as_float((unsigned)(sc->cand_pack[c] >> 32)));
    int row = sc->cand[c];
    int ms = (int)(sc->cand_pack[c] & 0xffffffffu);
    if (v > bestv || (v == bestv && row < bestrow)) { bestv = v; bestrow = row; bestms = ms; }
  }
  sc->s_idx = bestrow;
  sc->s_star = bestv;
  sc->mstar_idx = bestms;
}

// ------------------------------------------------- w_dist^2 of m_star to whole bank
__global__ void wdist_kernel(const float* __restrict__ lib, const Scal* __restrict__ sc,
                             float* __restrict__ wdist2) {
  int wave = threadIdx.x >> 6, lane = threadIdx.x & 63;
  int j = blockIdx.x * 4 + wave;
  int ms = sc->mstar_idx;
  float acc = 0.f;
#pragma unroll
  for (int k = 0; k < 12; k++) {
    int d = lane + 64 * k;
    float diff = lib[(size_t)j * DIM + d] - lib[(size_t)ms * DIM + d];
    acc += diff * diff;
  }
  acc = wave_reduce_sum(acc);
  if (lane == 0) wdist2[j] = acc;
}

// ------------------------------------------------- top-3 smallest + final scalar s
__global__ void top3_kernel(const float* __restrict__ wdist2,
                            const float* __restrict__ patch, const float* __restrict__ lib,
                            const float* __restrict__ meanp, const float* __restrict__ stdp,
                            const Scal* __restrict__ sc, float* __restrict__ out) {
  __shared__ float svals[768];
  __shared__ int   sidx[768];
  __shared__ int   nn[3];
  int t = threadIdx.x;

  float v0 = FLT_MAX_, v1 = FLT_MAX_, v2 = FLT_MAX_;
  int i0 = -1, i1 = -1, i2 = -1;
  for (int j = t; j < N_LIB; j += 256) {
    float v = wdist2[j];
    if (v < v0)      { v2=v1;i2=i1; v1=v0;i1=i0; v0=v;i0=j; }
    else if (v < v1) { v2=v1;i2=i1; v1=v;i1=j; }
    else if (v < v2) { v2=v;i2=j; }
  }
  svals[t*3+0]=v0; sidx[t*3+0]=i0;
  svals[t*3+1]=v1; sidx[t*3+1]=i1;
  svals[t*3+2]=v2; sidx[t*3+2]=i2;
  __syncthreads();

  if (t == 0) {
    float b0=FLT_MAX_,b1=FLT_MAX_,b2v=FLT_MAX_; int j0=-1,j1=-1,j2=-1;
    for (int e = 0; e < 768; e++) {
      float v = svals[e]; int j = sidx[e];
      if (j < 0) continue;
      if (v < b0 || (v == b0 && j < j0))      { b2v=b1;j2=j1; b1=b0;j1=j0; b0=v;j0=j; }
      else if (v < b1 || (v == b1 && j < j1)) { b2v=b1;j2=j1; b1=v;j1=j; }
      else if (v < b2v || (v == b2v && j < j2)) { b2v=v;j2=j; }
    }
    nn[0]=j0; nn[1]=j1; nn[2]=j2;
  }
  __syncthreads();

  if (t < 64) {
    int lane = t;
    int srow = sc->s_idx;
    float mu = meanp[0], sd = stdp[0];
    float accA = 0.f, accB = 0.f;
    int nA = nn[1], nB = nn[2];
#pragma unroll
    for (int k = 0; k < 12; k++) {
      int d = lane + 64 * k;
      float pvv = (patch[(size_t)srow * DIM + d] - mu) / sd;
      float dA = pvv - lib[(size_t)nA * DIM + d];
      float dB = pvv - lib[(size_t)nB * DIM + d];
      accA += dA * dA; accB += dB * dB;
    }
    accA = wave_reduce_sum(accA);
    accB = wave_reduce_sum(accB);
    if (lane == 0) {
      float dsq = sqrtf((float)DIM);
      float d1 = sqrtf(accA), d2 = sqrtf(accB);
      float sstar = sc->s_star;
      float w = 1.0f - expf(sstar / dsq) / (expf(d1 / dsq) + expf(d2 / dsq));
      out[0] = w * sstar;
    }
  }
}

// ------------------------------------------------- bilinear 56->224 (half-pixel, clamped)
__global__ void resize_kernel(const float* __restrict__ mv, float* __restrict__ rz) {
  int o = blockIdx.x * 256 + threadIdx.x;
  if (o >= IMGSZ * IMGSZ) return;
  int y = o / IMGSZ, x = o % IMGSZ;
  float sy = 0.25f * y - 0.375f; sy = fminf(fmaxf(sy, 0.0f), 55.0f);
  float sx = 0.25f * x - 0.375f; sx = fminf(fmaxf(sx, 0.0f), 55.0f);
  int y0 = (int)sy; if (y0 > 54) y0 = 54;
  int x0 = (int)sx; if (x0 > 54) x0 = 54;
  float fy = sy - y0, fx = sx - x0;
  float v00 = mv[y0*FM + x0],     v01 = mv[y0*FM + x0 + 1];
  float v10 = mv[(y0+1)*FM + x0], v11 = mv[(y0+1)*FM + x0 + 1];
  float a = v00 + fx * (v01 - v00);
  float b = v10 + fx * (v11 - v10);
  rz[o] = a + fy * (b - a);
}

// ------------------------------------------------- 9x9 gaussian, sigma 4, reflect pad
__global__ void blur_kernel(const float* __restrict__ rz, float* __restrict__ out) {
  int o = blockIdx.x * 256 + threadIdx.x;
  if (o >= IMGSZ * IMGSZ) return;
  int y = o / IMGSZ, x = o % IMGSZ;
  float g[9]; float gs = 0.f;
#pragma unroll
  for (int i = 0; i < 9; i++) { float tt = (float)(i - 4); g[i] = expf(-(tt*tt)/32.0f); gs += g[i]; }
#pragma unroll
  for (int i = 0; i < 9; i++) g[i] /= gs;
  float acc = 0.f;
#pragma unroll
  for (int dy = 0; dy < 9; dy++) {
    int yy = y + dy - 4;
    yy = yy < 0 ? -yy : (yy > IMGSZ - 1 ? 2*(IMGSZ-1) - yy : yy);
    float ra = 0.f;
#pragma unroll
    for (int dx = 0; dx < 9; dx++) {
      int xx = x + dx - 4;
      xx = xx < 0 ? -xx : (xx > IMGSZ - 1 ? 2*(IMGSZ-1) - xx : xx);
      ra += g[dx] * rz[yy*IMGSZ + xx];
    }
    acc += g[dy] * ra;
  }
  out[o] = acc;
}

// ================================================= host
extern "C" void kernel_launch(void* const* d_in, const int* in_sizes, int n_in,
                              void* d_out, int out_size, void* d_ws, size_t ws_size,
                              hipStream_t stream) {
  const float* patch = (const float*)d_in[0];
  const float* lib   = (const float*)d_in[1];
  const float* meanp = (const float*)d_in[2];
  const float* stdp  = (const float*)d_in[3];
  float* out = (float*)d_out;

  char* ws = (char*)d_ws;
  size_t off = 0;
  auto alloc = [&](size_t bytes) -> void* {
    void* p = ws + off;
    off = (off + bytes + 255) & ~(size_t)255;
    return p;
  };
  bf16_t* pb      = (bf16_t*)alloc((size_t)N_PATCH * DIM * sizeof(bf16_t));
  bf16_t* lb      = (bf16_t*)alloc((size_t)N_LIB * DIM * sizeof(bf16_t));
  float* a2       = (float*)alloc(N_PATCH * sizeof(float));
  float* b2       = (float*)alloc(N_LIB * sizeof(float));
  unsigned long long* minpack = (unsigned long long*)alloc(N_PATCH * 8);
  float* min_val  = (float*)alloc(N_PATCH * sizeof(float));
  int*   min_idx  = (int*)alloc(N_PATCH * sizeof(int));
  float* wdist2   = (float*)alloc(N_LIB * sizeof(float));
  float* resized  = (float*)alloc(IMGSZ * IMGSZ * sizeof(float));
  Scal*  sc       = (Scal*)alloc(sizeof(Scal));

  init_kernel<<<(N_PATCH + 255) / 256, 256, 0, stream>>>(minpack, sc);
  prep_patch_kernel<<<N_PATCH, 256, 0, stream>>>(patch, meanp, stdp, pb, a2);
  prep_lib_kernel<<<N_LIB, 256, 0, stream>>>(lib, lb, b2);
  gemm_min_kernel<<<dim3(25, 32), 256, 0, stream>>>(pb, lb, a2, b2, minpack);
  finalize_kernel<<<(N_PATCH + 255) / 256, 256, 0, stream>>>(minpack, min_val, min_idx, sc);
  collect_kernel<<<(N_PATCH + 255) / 256, 256, 0, stream>>>(min_val, sc);
  refine_kernel<<<dim3(64, 32), 256, 0, stream>>>(patch, lib, meanp, stdp, sc);
  pick_kernel<<<1, 64, 0, stream>>>(sc);
  wdist_kernel<<<N_LIB / 4, 256, 0, stream>>>(lib, sc, wdist2);
  top3_kernel<<<1, 256, 0, stream>>>(wdist2, patch, lib, meanp, stdp, sc, out);
  resize_kernel<<<(IMGSZ * IMGSZ + 255) / 256, 256, 0, stream>>>(min_val, resized);
  blur_kernel<<<(IMGSZ * IMGSZ + 255) / 256, 256, 0, stream>>>(resized, out + 1);
}

// Round 2
// 530.721 us; speedup vs baseline: 1.2180x; 1.2180x over previous
//
#include <hip/hip_runtime.h>
#include <hip/hip_bf16.h>
#include <stdint.h>

// Problem constants
#define N_PATCH 3136     // 56*56 query rows
#define N_LIB   16384    // memory bank rows
#define DIM     768
#define IMGSZ   224
#define FM      56

// GEMM tiling
#define BK 32
#define KT 24            // DIM/BK
#define NT 2             // 128-col n-tiles per block
#define LDS_STRIDE 40    // padded row stride (bf16): rows are 20 banks -> 2-way max (free)
#define MT 25            // ceil(3136/128)
#define NGRP 64          // n groups (each NT*128 = 256 cols); MT*NGRP = 1600 blocks

typedef __bf16 bf16_t;
typedef __bf16 bf16x8 __attribute__((ext_vector_type(8)));
typedef __bf16 bf16x4_v __attribute__((ext_vector_type(4)));
typedef float  f32x4  __attribute__((ext_vector_type(4)));

#define FLT_MAX_ 3.402823466e+38f

struct Scal {
  unsigned long long approx_max_pack;   // (bits(min_val)<<32) | (0xffffffff - row)
  unsigned long long cand_pack[64];     // per-candidate exact (bits(d2)<<32)|argmin_j
  int cand[64];
  int cand_count;
  int s_idx;
  float s_star;
  int mstar_idx;
};

__device__ __forceinline__ float wave_reduce_sum(float v) {
#pragma unroll
  for (int s = 32; s > 0; s >>= 1) v += __shfl_xor(v, s, 64);
  return v;
}

__device__ __forceinline__ unsigned long long shfl_xor_u64(unsigned long long v, int mask) {
  unsigned lo = (unsigned)v, hi = (unsigned)(v >> 32);
  lo = __shfl_xor(lo, mask, 64);
  hi = __shfl_xor(hi, mask, 64);
  return ((unsigned long long)hi << 32) | lo;
}

// ---------------------------------------------------------------- init
__global__ void init_kernel(unsigned long long* __restrict__ minpack, Scal* sc) {
  int i = blockIdx.x * 256 + threadIdx.x;
  if (i < N_PATCH) minpack[i] = ~0ULL;
  if (i < 64) sc->cand_pack[i] = ~0ULL;
  if (i == 0) {
    sc->approx_max_pack = 0ULL;
    sc->cand_count = 0;
    sc->s_idx = 0; sc->s_star = 0.f; sc->mstar_idx = 0;
  }
}

// ------------------------------------------------- prep: normalize + bf16 + norms
// block = 192 threads (3 waves), one row; thread t handles float4 at t*4
__global__ void prep_patch_kernel(const float* __restrict__ patch,
                                  const float* __restrict__ meanp,
                                  const float* __restrict__ stdp,
                                  bf16_t* __restrict__ pb, float* __restrict__ a2) {
  __shared__ float sbuf[3];
  int row = blockIdx.x;
  int t = threadIdx.x;
  float mu = meanp[0], sd = stdp[0];
  float4 v = ((const float4*)(patch + (size_t)row * DIM))[t];
  v.x = (v.x - mu) / sd; v.y = (v.y - mu) / sd;
  v.z = (v.z - mu) / sd; v.w = (v.w - mu) / sd;
  bf16x4_v o = {(__bf16)v.x, (__bf16)v.y, (__bf16)v.z, (__bf16)v.w};
  *(bf16x4_v*)(pb + (size_t)row * DIM + t * 4) = o;
  float acc = v.x*v.x + v.y*v.y + v.z*v.z + v.w*v.w;
  acc = wave_reduce_sum(acc);
  if ((t & 63) == 0) sbuf[t >> 6] = acc;
  __syncthreads();
  if (t == 0) a2[row] = sbuf[0] + sbuf[1] + sbuf[2];
}

__global__ void prep_lib_kernel(const float* __restrict__ lib,
                                bf16_t* __restrict__ lb, float* __restrict__ b2) {
  __shared__ float sbuf[3];
  int row = blockIdx.x;
  int t = threadIdx.x;
  float4 v = ((const float4*)(lib + (size_t)row * DIM))[t];
  bf16x4_v o = {(__bf16)v.x, (__bf16)v.y, (__bf16)v.z, (__bf16)v.w};
  *(bf16x4_v*)(lb + (size_t)row * DIM + t * 4) = o;
  float acc = v.x*v.x + v.y*v.y + v.z*v.z + v.w*v.w;
  acc = wave_reduce_sum(acc);
  if ((t & 63) == 0) sbuf[t >> 6] = acc;
  __syncthreads();
  if (t == 0) b2[row] = sbuf[0] + sbuf[1] + sbuf[2];
}

// ------------------------------------------------- fused bf16 GEMM + row-min
// 1600 blocks (XCD-swizzled), 256 threads = 4 waves; block tile 128(M) x 256(N)
// processed as 2 n-tiles of 128; flat software pipeline over (nt,kt) with
// register prefetch + LDS double buffer, ONE barrier per K-step.
__global__ __launch_bounds__(256, 2)
void gemm_min_kernel(const bf16_t* __restrict__ pb, const bf16_t* __restrict__ lb,
                     const float* __restrict__ a2, const float* __restrict__ b2,
                     unsigned long long* __restrict__ minpack) {
  __shared__ __align__(16) bf16_t As[2][128 * LDS_STRIDE];
  __shared__ __align__(16) bf16_t Bs[2][128 * LDS_STRIDE];

  const int t = threadIdx.x;
  const int wave = t >> 6;
  const int lane = t & 63;
  const int l15 = lane & 15;
  const int quad = lane >> 4;
  const int wm = (wave >> 1) * 64;
  const int wn = (wave & 1) * 64;

  // XCD-aware swizzle: all blocks on one XCD share 8 n-groups -> L2-resident lb slice
  const int lid = blockIdx.x;
  const int xcd = lid & 7;
  const int slot = lid >> 3;              // 0..199
  const int ygrp = xcd + 8 * (slot / MT); // 0..63
  const int mtile = slot % MT;
  const int m0 = mtile * 128;
  const int n_base = ygrp * (NT * 128);

  const int srow = t >> 2;                // 0..63
  const int scol = (t & 3) * 8;           // 0,8,16,24 (bf16 elems)

  int gr0 = m0 + srow;      if (gr0 > N_PATCH - 1) gr0 = N_PATCH - 1;
  int gr1 = m0 + srow + 64; if (gr1 > N_PATCH - 1) gr1 = N_PATCH - 1;
  const bf16_t* pA0 = pb + (size_t)gr0 * DIM + scol;
  const bf16_t* pA1 = pb + (size_t)gr1 * DIM + scol;
  const bf16_t* pB0 = lb + (size_t)(n_base + srow) * DIM + scol;
  const bf16_t* pB1 = pB0 + (size_t)64 * DIM;

  const int woff = srow * LDS_STRIDE + scol;

  // prologue: stage tile (nt=0, kt=0) into buffer 0
  {
    uint4 va0 = *(const uint4*)(pA0);
    uint4 va1 = *(const uint4*)(pA1);
    uint4 vb0 = *(const uint4*)(pB0);
    uint4 vb1 = *(const uint4*)(pB1);
    *(uint4*)(&As[0][woff]) = va0;
    *(uint4*)(&As[0][woff + 64 * LDS_STRIDE]) = va1;
    *(uint4*)(&Bs[0][woff]) = vb0;
    *(uint4*)(&Bs[0][woff + 64 * LDS_STRIDE]) = vb1;
  }
  __syncthreads();

  unsigned long long runmin[16];
#pragma unroll
  for (int i = 0; i < 16; i++) runmin[i] = ~0ULL;

  f32x4 acc[4][4];
#pragma unroll
  for (int mi = 0; mi < 4; mi++)
#pragma unroll
    for (int ni = 0; ni < 4; ni++) { f32x4 z = {0.f,0.f,0.f,0.f}; acc[mi][ni] = z; }

  int kt = 0, nt = 0;
  for (int i = 0; i < NT * KT; ++i) {
    const int cur = i & 1, nxt = cur ^ 1;
    int kt1 = kt + 1, nt1 = nt;
    if (kt1 == KT) { kt1 = 0; nt1++; }
    const bool hn = (nt1 < NT);

    // issue next tile's global loads (hidden behind the MFMAs below)
    uint4 va0, va1, vb0, vb1;
    if (hn) {
      size_t ka = (size_t)kt1 * BK;
      size_t kb = (size_t)nt1 * 128 * DIM + (size_t)kt1 * BK;
      va0 = *(const uint4*)(pA0 + ka);
      va1 = *(const uint4*)(pA1 + ka);
      vb0 = *(const uint4*)(pB0 + kb);
      vb1 = *(const uint4*)(pB1 + kb);
    }

    // compute current tile from LDS
    bf16x8 afr[4], bfr[4];
#pragma unroll
    for (int mi = 0; mi < 4; mi++)
      afr[mi] = *(const bf16x8*)(&As[cur][(wm + mi * 16 + l15) * LDS_STRIDE + quad * 8]);
#pragma unroll
    for (int ni = 0; ni < 4; ni++)
      bfr[ni] = *(const bf16x8*)(&Bs[cur][(wn + ni * 16 + l15) * LDS_STRIDE + quad * 8]);
#pragma unroll
    for (int mi = 0; mi < 4; mi++)
#pragma unroll
      for (int ni = 0; ni < 4; ni++)
        acc[mi][ni] = __builtin_amdgcn_mfma_f32_16x16x32_bf16(afr[mi], bfr[ni],
                                                              acc[mi][ni], 0, 0, 0);

    // epilogue at the end of each n-tile: d2 = a2 + b2 - 2*dot, packed row-min
    if (kt == KT - 1) {
      const int n0 = n_base + nt * 128;
      float b2n[4];
#pragma unroll
      for (int ni = 0; ni < 4; ni++) b2n[ni] = b2[n0 + wn + ni * 16 + l15];
#pragma unroll
      for (int mi = 0; mi < 4; mi++) {
#pragma unroll
        for (int r = 0; r < 4; r++) {
          int mrow = m0 + wm + mi * 16 + quad * 4 + r;
          float a2v = a2[mrow < N_PATCH ? mrow : (N_PATCH - 1)];
          unsigned long long best = ~0ULL;
#pragma unroll
          for (int ni = 0; ni < 4; ni++) {
            // C/D layout: col = lane&15, row = quad*4 + reg  [m89/m91]
            float d2v = a2v + b2n[ni] - 2.0f * acc[mi][ni][r];
            d2v = fmaxf(d2v, 0.0f);
            unsigned n = (unsigned)(n0 + wn + ni * 16 + l15);
            unsigned long long pk = (((unsigned long long)__float_as_uint(d2v)) << 32) | n;
            if (pk < best) best = pk;
          }
#pragma unroll
          for (int s = 1; s < 16; s <<= 1) {
            unsigned long long o = shfl_xor_u64(best, s);
            if (o < best) best = o;
          }
          if (best < runmin[mi * 4 + r]) runmin[mi * 4 + r] = best;
        }
      }
#pragma unroll
      for (int mi = 0; mi < 4; mi++)
#pragma unroll
        for (int ni = 0; ni < 4; ni++) { f32x4 z = {0.f,0.f,0.f,0.f}; acc[mi][ni] = z; }
    }

    // write prefetched tile into the other buffer; single barrier covers
    // (a) this write visible to next iter's readers, (b) all reads of buf[cur]
    // done before it is overwritten at i+2.
    if (hn) {
      *(uint4*)(&As[nxt][woff]) = va0;
      *(uint4*)(&As[nxt][woff + 64 * LDS_STRIDE]) = va1;
      *(uint4*)(&Bs[nxt][woff]) = vb0;
      *(uint4*)(&Bs[nxt][woff + 64 * LDS_STRIDE]) = vb1;
    }
    __syncthreads();
    kt = kt1; nt = nt1;
  }

  if (l15 == 0) {
#pragma unroll
    for (int mi = 0; mi < 4; mi++)
#pragma unroll
      for (int r = 0; r < 4; r++) {
        int mrow = m0 + wm + mi * 16 + quad * 4 + r;
        if (mrow < N_PATCH) atomicMin(&minpack[mrow], runmin[mi * 4 + r]);
      }
  }
}

// ------------------------------------------------- finalize rows + approx argmax
__global__ void finalize_kernel(const unsigned long long* __restrict__ minpack,
                                float* __restrict__ min_val, int* __restrict__ min_idx,
                                Scal* sc) {
  int i = blockIdx.x * 256 + threadIdx.x;
  if (i >= N_PATCH) return;
  unsigned long long p = minpack[i];
  float d2 = __uint_as_float((unsigned)(p >> 32));
  float v = sqrtf(d2);
  min_val[i] = v;
  min_idx[i] = (int)(p & 0xffffffffu);
  unsigned long long mp = (((unsigned long long)__float_as_uint(v)) << 32) |
                          (unsigned)(0xffffffffu - (unsigned)i);
  atomicMax(&sc->approx_max_pack, mp);
}

// ------------------------------------------------- collect argmax candidates
__global__ void collect_kernel(const float* __restrict__ min_val, Scal* sc) {
  int i = blockIdx.x * 256 + threadIdx.x;
  if (i >= N_PATCH) return;
  float amax = __uint_as_float((unsigned)(sc->approx_max_pack >> 32));
  if (min_val[i] >= amax - 0.02f) {   // >6 sigma of bf16 noise
    int p = atomicAdd(&sc->cand_count, 1);
    if (p < 64) sc->cand[p] = i;
  }
}

// ------------------------------------------------- exact fp32 refine of candidates
// grid (64 candidates, 128 chunks of 128 rows), block 256 = 4 waves x 32 rows
__global__ void refine_kernel(const float* __restrict__ patch, const float* __restrict__ lib,
                              const float* __restrict__ meanp, const float* __restrict__ stdp,
                              Scal* sc) {
  int c = blockIdx.x;
  int cnt = sc->cand_count; if (cnt > 64) cnt = 64;
  if (c >= cnt) return;
  int row = sc->cand[c];
  int wave = threadIdx.x >> 6, lane = threadIdx.x & 63;
  float mu = meanp[0], sd = stdp[0];
  float4 pv[3];
#pragma unroll
  for (int k = 0; k < 3; k++) {
    float4 v = ((const float4*)(patch + (size_t)row * DIM))[lane + 64 * k];
    v.x = (v.x - mu) / sd; v.y = (v.y - mu) / sd;
    v.z = (v.z - mu) / sd; v.w = (v.w - mu) / sd;
    pv[k] = v;
  }
  unsigned long long best = ~0ULL;
  int jbase = blockIdx.y * 128 + wave * 32;
  for (int rr = 0; rr < 32; rr++) {
    int j = jbase + rr;
    const float4* pl = (const float4*)(lib + (size_t)j * DIM);
    float acc = 0.f;
#pragma unroll
    for (int k = 0; k < 3; k++) {
      float4 l = pl[lane + 64 * k];
      float dx = pv[k].x - l.x, dy = pv[k].y - l.y;
      float dz = pv[k].z - l.z, dw = pv[k].w - l.w;
      acc += dx*dx + dy*dy + dz*dz + dw*dw;
    }
    acc = wave_reduce_sum(acc);
    unsigned long long pk = (((unsigned long long)__float_as_uint(acc)) << 32) | (unsigned)j;
    if (pk < best) best = pk;
  }
  if (lane == 0) atomicMin(&sc->cand_pack[c], best);
}

// ------------------------------------------------- pick exact argmax
__global__ void pick_kernel(Scal* sc) {
  if (threadIdx.x != 0) return;
  int cnt = sc->cand_count; if (cnt > 64) cnt = 64;
  float bestv = -1.f; int bestrow = 0x7fffffff; int bestms = 0;
  for (int c = 0; c < cnt; c++) {
    float v = sqrtf(__uint_as_float((unsigned)(sc->cand_pack[c] >> 32)));
    int row = sc->cand[c];
    int ms = (int)(sc->cand_pack[c] & 0xffffffffu);
    if (v > bestv || (v == bestv && row < bestrow)) { bestv = v; bestrow = row; bestms = ms; }
  }
  sc->s_idx = bestrow;
  sc->s_star = bestv;
  sc->mstar_idx = bestms;
}

// ------------------------------------------------- w_dist^2 of m_star to whole bank
__global__ void wdist_kernel(const float* __restrict__ lib, const Scal* __restrict__ sc,
                             float* __restrict__ wdist2) {
  int wave = threadIdx.x >> 6, lane = threadIdx.x & 63;
  int j = blockIdx.x * 4 + wave;
  int ms = sc->mstar_idx;
  const float4* pj = (const float4*)(lib + (size_t)j * DIM);
  const float4* pm = (const float4*)(lib + (size_t)ms * DIM);
  float acc = 0.f;
#pragma unroll
  for (int k = 0; k < 3; k++) {
    float4 a = pj[lane + 64 * k], b = pm[lane + 64 * k];
    float dx = a.x - b.x, dy = a.y - b.y, dz = a.z - b.z, dw = a.w - b.w;
    acc += dx*dx + dy*dy + dz*dz + dw*dw;
  }
  acc = wave_reduce_sum(acc);
  if (lane == 0) wdist2[j] = acc;
}

// ------------------------------------------------- top-3 smallest + final scalar s
__global__ void top3_kernel(const float* __restrict__ wdist2,
                            const float* __restrict__ patch, const float* __restrict__ lib,
                            const float* __restrict__ meanp, const float* __restrict__ stdp,
                            const Scal* __restrict__ sc, float* __restrict__ out) {
  __shared__ float svals[768];
  __shared__ int   sidx[768];
  __shared__ int   nn[3];
  int t = threadIdx.x;

  float v0 = FLT_MAX_, v1 = FLT_MAX_, v2 = FLT_MAX_;
  int i0 = -1, i1 = -1, i2 = -1;
  for (int j = t; j < N_LIB; j += 256) {
    float v = wdist2[j];
    if (v < v0)      { v2=v1;i2=i1; v1=v0;i1=i0; v0=v;i0=j; }
    else if (v < v1) { v2=v1;i2=i1; v1=v;i1=j; }
    else if (v < v2) { v2=v;i2=j; }
  }
  svals[t*3+0]=v0; sidx[t*3+0]=i0;
  svals[t*3+1]=v1; sidx[t*3+1]=i1;
  svals[t*3+2]=v2; sidx[t*3+2]=i2;
  __syncthreads();

  if (t == 0) {
    float b0=FLT_MAX_,b1=FLT_MAX_,b2v=FLT_MAX_; int j0=-1,j1=-1,j2=-1;
    for (int e = 0; e < 768; e++) {
      float v = svals[e]; int j = sidx[e];
      if (j < 0) continue;
      if (v < b0 || (v == b0 && j < j0))      { b2v=b1;j2=j1; b1=b0;j1=j0; b0=v;j0=j; }
      else if (v < b1 || (v == b1 && j < j1)) { b2v=b1;j2=j1; b1=v;j1=j; }
      else if (v < b2v || (v == b2v && j < j2)) { b2v=v;j2=j; }
    }
    nn[0]=j0; nn[1]=j1; nn[2]=j2;
  }
  __syncthreads();

  if (t < 64) {
    int lane = t;
    int srow = sc->s_idx;
    float mu = meanp[0], sd = stdp[0];
    float accA = 0.f, accB = 0.f;
    int nA = nn[1], nB = nn[2];
#pragma unroll
    for (int k = 0; k < 12; k++) {
      int d = lane + 64 * k;
      float pvv = (patch[(size_t)srow * DIM + d] - mu) / sd;
      float dA = pvv - lib[(size_t)nA * DIM + d];
      float dB = pvv - lib[(size_t)nB * DIM + d];
      accA += dA * dA; accB += dB * dB;
    }
    accA = wave_reduce_sum(accA);
    accB = wave_reduce_sum(accB);
    if (lane == 0) {
      float dsq = sqrtf((float)DIM);
      float d1 = sqrtf(accA), d2 = sqrtf(accB);
      float sstar = sc->s_star;
      float w = 1.0f - expf(sstar / dsq) / (expf(d1 / dsq) + expf(d2 / dsq));
      out[0] = w * sstar;
    }
  }
}

// ------------------------------------------------- bilinear 56->224 (half-pixel, clamped)
__global__ void resize_kernel(const float* __restrict__ mv, float* __restrict__ rz) {
  int o = blockIdx.x * 256 + threadIdx.x;
  if (o >= IMGSZ * IMGSZ) return;
  int y = o / IMGSZ, x = o % IMGSZ;
  float sy = 0.25f * y - 0.375f; sy = fminf(fmaxf(sy, 0.0f), 55.0f);
  float sx = 0.25f * x - 0.375f; sx = fminf(fmaxf(sx, 0.0f), 55.0f);
  int y0 = (int)sy; if (y0 > 54) y0 = 54;
  int x0 = (int)sx; if (x0 > 54) x0 = 54;
  float fy = sy - y0, fx = sx - x0;
  float v00 = mv[y0*FM + x0],     v01 = mv[y0*FM + x0 + 1];
  float v10 = mv[(y0+1)*FM + x0], v11 = mv[(y0+1)*FM + x0 + 1];
  float a = v00 + fx * (v01 - v00);
  float b = v10 + fx * (v11 - v10);
  rz[o] = a + fy * (b - a);
}

// ------------------------------------------------- 9x9 gaussian, sigma 4, reflect pad
__global__ void blur_kernel(const float* __restrict__ rz, float* __restrict__ out) {
  int o = blockIdx.x * 256 + threadIdx.x;
  if (o >= IMGSZ * IMGSZ) return;
  int y = o / IMGSZ, x = o % IMGSZ;
  float g[9]; float gs = 0.f;
#pragma unroll
  for (int i = 0; i < 9; i++) { float tt = (float)(i - 4); g[i] = expf(-(tt*tt)/32.0f); gs += g[i]; }
#pragma unroll
  for (int i = 0; i < 9; i++) g[i] /= gs;
  float acc = 0.f;
#pragma unroll
  for (int dy = 0; dy < 9; dy++) {
    int yy = y + dy - 4;
    yy = yy < 0 ? -yy : (yy > IMGSZ - 1 ? 2*(IMGSZ-1) - yy : yy);
    float ra = 0.f;
#pragma unroll
    for (int dx = 0; dx < 9; dx++) {
      int xx = x + dx - 4;
      xx = xx < 0 ? -xx : (xx > IMGSZ - 1 ? 2*(IMGSZ-1) - xx : xx);
      ra += g[dx] * rz[yy*IMGSZ + xx];
    }
    acc += g[dy] * ra;
  }
  out[o] = acc;
}

// ================================================= host
extern "C" void kernel_launch(void* const* d_in, const int* in_sizes, int n_in,
                              void* d_out, int out_size, void* d_ws, size_t ws_size,
                              hipStream_t stream) {
  const float* patch = (const float*)d_in[0];
  const float* lib   = (const float*)d_in[1];
  const float* meanp = (const float*)d_in[2];
  const float* stdp  = (const float*)d_in[3];
  float* out = (float*)d_out;

  char* ws = (char*)d_ws;
  size_t off = 0;
  auto alloc = [&](size_t bytes) -> void* {
    void* p = ws + off;
    off = (off + bytes + 255) & ~(size_t)255;
    return p;
  };
  bf16_t* pb      = (bf16_t*)alloc((size_t)N_PATCH * DIM * sizeof(bf16_t));
  bf16_t* lb      = (bf16_t*)alloc((size_t)N_LIB * DIM * sizeof(bf16_t));
  float* a2       = (float*)alloc(N_PATCH * sizeof(float));
  float* b2       = (float*)alloc(N_LIB * sizeof(float));
  unsigned long long* minpack = (unsigned long long*)alloc(N_PATCH * 8);
  float* min_val  = (float*)alloc(N_PATCH * sizeof(float));
  int*   min_idx  = (int*)alloc(N_PATCH * sizeof(int));
  float* wdist2   = (float*)alloc(N_LIB * sizeof(float));
  float* resized  = (float*)alloc(IMGSZ * IMGSZ * sizeof(float));
  Scal*  sc       = (Scal*)alloc(sizeof(Scal));

  init_kernel<<<(N_PATCH + 255) / 256, 256, 0, stream>>>(minpack, sc);
  prep_patch_kernel<<<N_PATCH, 192, 0, stream>>>(patch, meanp, stdp, pb, a2);
  prep_lib_kernel<<<N_LIB, 192, 0, stream>>>(lib, lb, b2);
  gemm_min_kernel<<<MT * NGRP, 256, 0, stream>>>(pb, lb, a2, b2, minpack);
  finalize_kernel<<<(N_PATCH + 255) / 256, 256, 0, stream>>>(minpack, min_val, min_idx, sc);
  collect_kernel<<<(N_PATCH + 255) / 256, 256, 0, stream>>>(min_val, sc);
  refine_kernel<<<dim3(64, 128), 256, 0, stream>>>(patch, lib, meanp, stdp, sc);
  pick_kernel<<<1, 64, 0, stream>>>(sc);
  wdist_kernel<<<N_LIB / 4, 256, 0, stream>>>(lib, sc, wdist2);
  top3_kernel<<<1, 256, 0, stream>>>(wdist2, patch, lib, meanp, stdp, sc, out);
  resize_kernel<<<(IMGSZ * IMGSZ + 255) / 256, 256, 0, stream>>>(min_val, resized);
  blur_kernel<<<(IMGSZ * IMGSZ + 255) / 256, 256, 0, stream>>>(resized, out + 1);
}

// Round 3
// 368.835 us; speedup vs baseline: 1.7526x; 1.4389x over previous
//
#include <hip/hip_runtime.h>
#include <hip/hip_bf16.h>
#include <stdint.h>

// Problem constants
#define N_PATCH 3136     // 56*56 query rows
#define N_LIB   16384    // memory bank rows
#define DIM     768
#define IMGSZ   224
#define FM      56

// GEMM tiling
#define BK 32
#define KT 24            // DIM/BK
#define NT 2             // 128-col n-tiles per block
#define LDS_STRIDE 40    // padded row stride (bf16): rows are 20 banks -> 2-way max (free)
#define MT 25            // ceil(3136/128)
#define NGRP 64          // n groups (each NT*128 = 256 cols); MT*NGRP = 1600 blocks

typedef __bf16 bf16_t;
typedef __bf16 bf16x8 __attribute__((ext_vector_type(8)));
typedef __bf16 bf16x4_v __attribute__((ext_vector_type(4)));
typedef float  f32x4  __attribute__((ext_vector_type(4)));

#define FLT_MAX_ 3.402823466e+38f

struct Scal {
  unsigned long long approx_max_pack;   // (bits(min_val)<<32) | (0xffffffff - row)
  unsigned long long cand_pack[64];     // per-candidate exact (bits(d2)<<32)|argmin_j
  int cand[64];
  int cand_count;
  int s_idx;
  float s_star;
  int mstar_idx;
};

__device__ __forceinline__ float wave_reduce_sum(float v) {
#pragma unroll
  for (int s = 32; s > 0; s >>= 1) v += __shfl_xor(v, s, 64);
  return v;
}

__device__ __forceinline__ unsigned long long shfl_xor_u64(unsigned long long v, int mask) {
  unsigned lo = (unsigned)v, hi = (unsigned)(v >> 32);
  lo = __shfl_xor(lo, mask, 64);
  hi = __shfl_xor(hi, mask, 64);
  return ((unsigned long long)hi << 32) | lo;
}

// ---------------------------------------------------------------- init
__global__ void init_kernel(unsigned long long* __restrict__ minpack, Scal* sc) {
  int i = blockIdx.x * 256 + threadIdx.x;
  if (i < N_PATCH) minpack[i] = ~0ULL;
  if (i < 64) sc->cand_pack[i] = ~0ULL;
  if (i == 0) {
    sc->approx_max_pack = 0ULL;
    sc->cand_count = 0;
    sc->s_idx = 0; sc->s_star = 0.f; sc->mstar_idx = 0;
  }
}

// ------------------------------------------------- prep: normalize + bf16 + norms
// block = 192 threads (3 waves), one row; thread t handles float4 at t*4
__global__ void prep_patch_kernel(const float* __restrict__ patch,
                                  const float* __restrict__ meanp,
                                  const float* __restrict__ stdp,
                                  bf16_t* __restrict__ pb, float* __restrict__ a2) {
  __shared__ float sbuf[3];
  int row = blockIdx.x;
  int t = threadIdx.x;
  float mu = meanp[0], sd = stdp[0];
  float4 v = ((const float4*)(patch + (size_t)row * DIM))[t];
  v.x = (v.x - mu) / sd; v.y = (v.y - mu) / sd;
  v.z = (v.z - mu) / sd; v.w = (v.w - mu) / sd;
  bf16x4_v o = {(__bf16)v.x, (__bf16)v.y, (__bf16)v.z, (__bf16)v.w};
  *(bf16x4_v*)(pb + (size_t)row * DIM + t * 4) = o;
  float acc = v.x*v.x + v.y*v.y + v.z*v.z + v.w*v.w;
  acc = wave_reduce_sum(acc);
  if ((t & 63) == 0) sbuf[t >> 6] = acc;
  __syncthreads();
  if (t == 0) a2[row] = sbuf[0] + sbuf[1] + sbuf[2];
}

__global__ void prep_lib_kernel(const float* __restrict__ lib,
                                bf16_t* __restrict__ lb, float* __restrict__ b2) {
  __shared__ float sbuf[3];
  int row = blockIdx.x;
  int t = threadIdx.x;
  float4 v = ((const float4*)(lib + (size_t)row * DIM))[t];
  bf16x4_v o = {(__bf16)v.x, (__bf16)v.y, (__bf16)v.z, (__bf16)v.w};
  *(bf16x4_v*)(lb + (size_t)row * DIM + t * 4) = o;
  float acc = v.x*v.x + v.y*v.y + v.z*v.z + v.w*v.w;
  acc = wave_reduce_sum(acc);
  if ((t & 63) == 0) sbuf[t >> 6] = acc;
  __syncthreads();
  if (t == 0) b2[row] = sbuf[0] + sbuf[1] + sbuf[2];
}

// ------------------------------------------------- fused bf16 GEMM + row-min
__global__ __launch_bounds__(256, 2)
void gemm_min_kernel(const bf16_t* __restrict__ pb, const bf16_t* __restrict__ lb,
                     const float* __restrict__ a2, const float* __restrict__ b2,
                     unsigned long long* __restrict__ minpack) {
  __shared__ __align__(16) bf16_t As[2][128 * LDS_STRIDE];
  __shared__ __align__(16) bf16_t Bs[2][128 * LDS_STRIDE];

  const int t = threadIdx.x;
  const int wave = t >> 6;
  const int lane = t & 63;
  const int l15 = lane & 15;
  const int quad = lane >> 4;
  const int wm = (wave >> 1) * 64;
  const int wn = (wave & 1) * 64;

  const int lid = blockIdx.x;
  const int xcd = lid & 7;
  const int slot = lid >> 3;              // 0..199
  const int ygrp = xcd + 8 * (slot / MT); // 0..63
  const int mtile = slot % MT;
  const int m0 = mtile * 128;
  const int n_base = ygrp * (NT * 128);

  const int srow = t >> 2;                // 0..63
  const int scol = (t & 3) * 8;           // 0,8,16,24 (bf16 elems)

  int gr0 = m0 + srow;      if (gr0 > N_PATCH - 1) gr0 = N_PATCH - 1;
  int gr1 = m0 + srow + 64; if (gr1 > N_PATCH - 1) gr1 = N_PATCH - 1;
  const bf16_t* pA0 = pb + (size_t)gr0 * DIM + scol;
  const bf16_t* pA1 = pb + (size_t)gr1 * DIM + scol;
  const bf16_t* pB0 = lb + (size_t)(n_base + srow) * DIM + scol;
  const bf16_t* pB1 = pB0 + (size_t)64 * DIM;

  const int woff = srow * LDS_STRIDE + scol;

  {
    uint4 va0 = *(const uint4*)(pA0);
    uint4 va1 = *(const uint4*)(pA1);
    uint4 vb0 = *(const uint4*)(pB0);
    uint4 vb1 = *(const uint4*)(pB1);
    *(uint4*)(&As[0][woff]) = va0;
    *(uint4*)(&As[0][woff + 64 * LDS_STRIDE]) = va1;
    *(uint4*)(&Bs[0][woff]) = vb0;
    *(uint4*)(&Bs[0][woff + 64 * LDS_STRIDE]) = vb1;
  }
  __syncthreads();

  unsigned long long runmin[16];
#pragma unroll
  for (int i = 0; i < 16; i++) runmin[i] = ~0ULL;

  f32x4 acc[4][4];
#pragma unroll
  for (int mi = 0; mi < 4; mi++)
#pragma unroll
    for (int ni = 0; ni < 4; ni++) { f32x4 z = {0.f,0.f,0.f,0.f}; acc[mi][ni] = z; }

  int kt = 0, nt = 0;
  for (int i = 0; i < NT * KT; ++i) {
    const int cur = i & 1, nxt = cur ^ 1;
    int kt1 = kt + 1, nt1 = nt;
    if (kt1 == KT) { kt1 = 0; nt1++; }
    const bool hn = (nt1 < NT);

    uint4 va0, va1, vb0, vb1;
    if (hn) {
      size_t ka = (size_t)kt1 * BK;
      size_t kb = (size_t)nt1 * 128 * DIM + (size_t)kt1 * BK;
      va0 = *(const uint4*)(pA0 + ka);
      va1 = *(const uint4*)(pA1 + ka);
      vb0 = *(const uint4*)(pB0 + kb);
      vb1 = *(const uint4*)(pB1 + kb);
    }

    bf16x8 afr[4], bfr[4];
#pragma unroll
    for (int mi = 0; mi < 4; mi++)
      afr[mi] = *(const bf16x8*)(&As[cur][(wm + mi * 16 + l15) * LDS_STRIDE + quad * 8]);
#pragma unroll
    for (int ni = 0; ni < 4; ni++)
      bfr[ni] = *(const bf16x8*)(&Bs[cur][(wn + ni * 16 + l15) * LDS_STRIDE + quad * 8]);
#pragma unroll
    for (int mi = 0; mi < 4; mi++)
#pragma unroll
      for (int ni = 0; ni < 4; ni++)
        acc[mi][ni] = __builtin_amdgcn_mfma_f32_16x16x32_bf16(afr[mi], bfr[ni],
                                                              acc[mi][ni], 0, 0, 0);

    if (kt == KT - 1) {
      const int n0 = n_base + nt * 128;
      float b2n[4];
#pragma unroll
      for (int ni = 0; ni < 4; ni++) b2n[ni] = b2[n0 + wn + ni * 16 + l15];
#pragma unroll
      for (int mi = 0; mi < 4; mi++) {
#pragma unroll
        for (int r = 0; r < 4; r++) {
          int mrow = m0 + wm + mi * 16 + quad * 4 + r;
          float a2v = a2[mrow < N_PATCH ? mrow : (N_PATCH - 1)];
          unsigned long long best = ~0ULL;
#pragma unroll
          for (int ni = 0; ni < 4; ni++) {
            // C/D layout: col = lane&15, row = quad*4 + reg  [m89/m91]
            float d2v = a2v + b2n[ni] - 2.0f * acc[mi][ni][r];
            d2v = fmaxf(d2v, 0.0f);
            unsigned n = (unsigned)(n0 + wn + ni * 16 + l15);
            unsigned long long pk = (((unsigned long long)__float_as_uint(d2v)) << 32) | n;
            if (pk < best) best = pk;
          }
#pragma unroll
          for (int s = 1; s < 16; s <<= 1) {
            unsigned long long o = shfl_xor_u64(best, s);
            if (o < best) best = o;
          }
          if (best < runmin[mi * 4 + r]) runmin[mi * 4 + r] = best;
        }
      }
#pragma unroll
      for (int mi = 0; mi < 4; mi++)
#pragma unroll
        for (int ni = 0; ni < 4; ni++) { f32x4 z = {0.f,0.f,0.f,0.f}; acc[mi][ni] = z; }
    }

    if (hn) {
      *(uint4*)(&As[nxt][woff]) = va0;
      *(uint4*)(&As[nxt][woff + 64 * LDS_STRIDE]) = va1;
      *(uint4*)(&Bs[nxt][woff]) = vb0;
      *(uint4*)(&Bs[nxt][woff + 64 * LDS_STRIDE]) = vb1;
    }
    __syncthreads();
    kt = kt1; nt = nt1;
  }

  if (l15 == 0) {
#pragma unroll
    for (int mi = 0; mi < 4; mi++)
#pragma unroll
      for (int r = 0; r < 4; r++) {
        int mrow = m0 + wm + mi * 16 + quad * 4 + r;
        if (mrow < N_PATCH) atomicMin(&minpack[mrow], runmin[mi * 4 + r]);
      }
  }
}

// ------------------------------------------------- finalize rows + approx argmax
__global__ void finalize_kernel(const unsigned long long* __restrict__ minpack,
                                float* __restrict__ min_val, int* __restrict__ min_idx,
                                Scal* sc) {
  int i = blockIdx.x * 256 + threadIdx.x;
  if (i >= N_PATCH) return;
  unsigned long long p = minpack[i];
  float d2 = __uint_as_float((unsigned)(p >> 32));
  float v = sqrtf(d2);
  min_val[i] = v;
  min_idx[i] = (int)(p & 0xffffffffu);
  unsigned long long mp = (((unsigned long long)__float_as_uint(v)) << 32) |
                          (unsigned)(0xffffffffu - (unsigned)i);
  atomicMax(&sc->approx_max_pack, mp);
}

// ------------------------------------------------- collect argmax candidates
__global__ void collect_kernel(const float* __restrict__ min_val, Scal* sc) {
  int i = blockIdx.x * 256 + threadIdx.x;
  if (i >= N_PATCH) return;
  float amax = __uint_as_float((unsigned)(sc->approx_max_pack >> 32));
  if (min_val[i] >= amax - 0.02f) {   // >6 sigma of bf16 noise
    int p = atomicAdd(&sc->cand_count, 1);
    if (p < 64) sc->cand[p] = i;
  }
}

// ------------------------------------------------- exact fp32 refine of candidates
// grid (64 candidates, 128 chunks of 128 rows), block 256 = 4 waves x 32 rows
__global__ void refine_kernel(const float* __restrict__ patch, const float* __restrict__ lib,
                              const float* __restrict__ meanp, const float* __restrict__ stdp,
                              Scal* sc) {
  int c = blockIdx.x;
  int cnt = sc->cand_count; if (cnt > 64) cnt = 64;
  if (c >= cnt) return;
  int row = sc->cand[c];
  int wave = threadIdx.x >> 6, lane = threadIdx.x & 63;
  float mu = meanp[0], sd = stdp[0];
  float4 pv[3];
#pragma unroll
  for (int k = 0; k < 3; k++) {
    float4 v = ((const float4*)(patch + (size_t)row * DIM))[lane + 64 * k];
    v.x = (v.x - mu) / sd; v.y = (v.y - mu) / sd;
    v.z = (v.z - mu) / sd; v.w = (v.w - mu) / sd;
    pv[k] = v;
  }
  unsigned long long best = ~0ULL;
  int jbase = blockIdx.y * 128 + wave * 32;
  for (int rr = 0; rr < 32; rr++) {
    int j = jbase + rr;
    const float4* pl = (const float4*)(lib + (size_t)j * DIM);
    float acc = 0.f;
#pragma unroll
    for (int k = 0; k < 3; k++) {
      float4 l = pl[lane + 64 * k];
      float dx = pv[k].x - l.x, dy = pv[k].y - l.y;
      float dz = pv[k].z - l.z, dw = pv[k].w - l.w;
      acc += dx*dx + dy*dy + dz*dz + dw*dw;
    }
    acc = wave_reduce_sum(acc);
    unsigned long long pk = (((unsigned long long)__float_as_uint(acc)) << 32) | (unsigned)j;
    if (pk < best) best = pk;
  }
  if (lane == 0) atomicMin(&sc->cand_pack[c], best);
}

// ------------------------------------------------- pick exact argmax (1 wave, parallel)
__global__ void pick_kernel(Scal* sc) {
  int lane = threadIdx.x;   // 64 threads
  int cnt = sc->cand_count; if (cnt > 64) cnt = 64;
  unsigned long long pk = 0ULL;
  int row = 0, ms = 0;
  if (lane < cnt) {
    unsigned long long cp = sc->cand_pack[lane];
    row = sc->cand[lane];
    ms = (int)(cp & 0xffffffffu);
    unsigned d2b = (unsigned)(cp >> 32);
    pk = (((unsigned long long)d2b) << 32) | (unsigned)(0xffffffffu - (unsigned)row);
  }
  unsigned long long m = pk;
#pragma unroll
  for (int s = 1; s < 64; s <<= 1) {
    unsigned long long o = shfl_xor_u64(m, s);
    if (o > m) m = o;
  }
  if (lane < cnt && pk == m) {
    sc->s_idx = row;
    sc->s_star = sqrtf(__uint_as_float((unsigned)(m >> 32)));
    sc->mstar_idx = ms;
  }
}

// ------------------------------------------------- w_dist^2 of m_star to whole bank
__global__ void wdist_kernel(const float* __restrict__ lib, const Scal* __restrict__ sc,
                             float* __restrict__ wdist2) {
  int wave = threadIdx.x >> 6, lane = threadIdx.x & 63;
  int j = blockIdx.x * 4 + wave;
  int ms = sc->mstar_idx;
  const float4* pj = (const float4*)(lib + (size_t)j * DIM);
  const float4* pm = (const float4*)(lib + (size_t)ms * DIM);
  float acc = 0.f;
#pragma unroll
  for (int k = 0; k < 3; k++) {
    float4 a = pj[lane + 64 * k], b = pm[lane + 64 * k];
    float dx = a.x - b.x, dy = a.y - b.y, dz = a.z - b.z, dw = a.w - b.w;
    acc += dx*dx + dy*dy + dz*dz + dw*dw;
  }
  acc = wave_reduce_sum(acc);
  if (lane == 0) wdist2[j] = acc;
}

// ------------------------------------------------- top-3 smallest + final scalar s
// packed u64 keys (bits(d2)<<32 | j): unique, min => smallest value, tie -> smaller j
// (matches lax.top_k tie-breaking). Wave-parallel merge, no serial loops.
__global__ void top3_kernel(const float* __restrict__ wdist2,
                            const float* __restrict__ patch, const float* __restrict__ lib,
                            const float* __restrict__ meanp, const float* __restrict__ stdp,
                            const Scal* __restrict__ sc, float* __restrict__ out) {
  __shared__ unsigned long long sl[768];
  int t = threadIdx.x;

  unsigned long long b0 = ~0ULL, b1 = ~0ULL, b2 = ~0ULL;
  for (int j = t; j < N_LIB; j += 256) {
    unsigned long long pk = (((unsigned long long)__float_as_uint(wdist2[j])) << 32) | (unsigned)j;
    if (pk < b0)      { b2 = b1; b1 = b0; b0 = pk; }
    else if (pk < b1) { b2 = b1; b1 = pk; }
    else if (pk < b2) { b2 = pk; }
  }
  sl[t * 3 + 0] = b0; sl[t * 3 + 1] = b1; sl[t * 3 + 2] = b2;
  __syncthreads();
  if (t >= 64) return;

  // wave 0: 12 entries per lane -> local sorted top-3
  unsigned long long c0 = ~0ULL, c1 = ~0ULL, c2 = ~0ULL;
#pragma unroll
  for (int e = 0; e < 12; e++) {
    unsigned long long pk = sl[t * 12 + e];
    if (pk < c0)      { c2 = c1; c1 = c0; c0 = pk; }
    else if (pk < c1) { c2 = c1; c1 = pk; }
    else if (pk < c2) { c2 = pk; }
  }
  // 3 rounds: global min via butterfly, remove winner locally (keys unique)
  unsigned long long res1 = 0, res2 = 0;
#pragma unroll
  for (int r = 0; r < 3; r++) {
    unsigned long long m = c0;
#pragma unroll
    for (int s = 1; s < 64; s <<= 1) {
      unsigned long long o = shfl_xor_u64(m, s);
      if (o < m) m = o;
    }
    if (r == 1) res1 = m;
    if (r == 2) res2 = m;
    if (c0 == m) { c0 = c1; c1 = c2; c2 = ~0ULL; }
  }
  int nA = (int)(res1 & 0xffffffffu);   // 2nd nearest
  int nB = (int)(res2 & 0xffffffffu);   // 3rd nearest

  int lane = t;
  int srow = sc->s_idx;
  float mu = meanp[0], sd = stdp[0];
  float accA = 0.f, accB = 0.f;
#pragma unroll
  for (int k = 0; k < 3; k++) {
    float4 p4 = ((const float4*)(patch + (size_t)srow * DIM))[lane + 64 * k];
    float4 a4 = ((const float4*)(lib + (size_t)nA * DIM))[lane + 64 * k];
    float4 b4 = ((const float4*)(lib + (size_t)nB * DIM))[lane + 64 * k];
    float px = (p4.x - mu) / sd, py = (p4.y - mu) / sd;
    float pz = (p4.z - mu) / sd, pw = (p4.w - mu) / sd;
    float dax = px - a4.x, day = py - a4.y, daz = pz - a4.z, daw = pw - a4.w;
    float dbx = px - b4.x, dby = py - b4.y, dbz = pz - b4.z, dbw = pw - b4.w;
    accA += dax*dax + day*day + daz*daz + daw*daw;
    accB += dbx*dbx + dby*dby + dbz*dbz + dbw*dbw;
  }
  accA = wave_reduce_sum(accA);
  accB = wave_reduce_sum(accB);
  if (lane == 0) {
    float dsq = sqrtf((float)DIM);
    float d1 = sqrtf(accA), d2v = sqrtf(accB);
    float sstar = sc->s_star;
    float w = 1.0f - expf(sstar / dsq) / (expf(d1 / dsq) + expf(d2v / dsq));
    out[0] = w * sstar;
  }
}

// ------------------------------------------------- bilinear 56->224 (half-pixel, clamped)
__global__ void resize_kernel(const float* __restrict__ mv, float* __restrict__ rz) {
  int o = blockIdx.x * 256 + threadIdx.x;
  if (o >= IMGSZ * IMGSZ) return;
  int y = o / IMGSZ, x = o % IMGSZ;
  float sy = 0.25f * y - 0.375f; sy = fminf(fmaxf(sy, 0.0f), 55.0f);
  float sx = 0.25f * x - 0.375f; sx = fminf(fmaxf(sx, 0.0f), 55.0f);
  int y0 = (int)sy; if (y0 > 54) y0 = 54;
  int x0 = (int)sx; if (x0 > 54) x0 = 54;
  float fy = sy - y0, fx = sx - x0;
  float v00 = mv[y0*FM + x0],     v01 = mv[y0*FM + x0 + 1];
  float v10 = mv[(y0+1)*FM + x0], v11 = mv[(y0+1)*FM + x0 + 1];
  float a = v00 + fx * (v01 - v00);
  float b = v10 + fx * (v11 - v10);
  rz[o] = a + fy * (b - a);
}

// ------------------------------------------------- 9x9 gaussian, sigma 4, reflect pad
__global__ void blur_kernel(const float* __restrict__ rz, float* __restrict__ out) {
  int o = blockIdx.x * 256 + threadIdx.x;
  if (o >= IMGSZ * IMGSZ) return;
  int y = o / IMGSZ, x = o % IMGSZ;
  float g[9]; float gs = 0.f;
#pragma unroll
  for (int i = 0; i < 9; i++) { float tt = (float)(i - 4); g[i] = expf(-(tt*tt)/32.0f); gs += g[i]; }
#pragma unroll
  for (int i = 0; i < 9; i++) g[i] /= gs;
  float acc = 0.f;
#pragma unroll
  for (int dy = 0; dy < 9; dy++) {
    int yy = y + dy - 4;
    yy = yy < 0 ? -yy : (yy > IMGSZ - 1 ? 2*(IMGSZ-1) - yy : yy);
    float ra = 0.f;
#pragma unroll
    for (int dx = 0; dx < 9; dx++) {
      int xx = x + dx - 4;
      xx = xx < 0 ? -xx : (xx > IMGSZ - 1 ? 2*(IMGSZ-1) - xx : xx);
      ra += g[dx] * rz[yy*IMGSZ + xx];
    }
    acc += g[dy] * ra;
  }
  out[o] = acc;
}

// ================================================= host
extern "C" void kernel_launch(void* const* d_in, const int* in_sizes, int n_in,
                              void* d_out, int out_size, void* d_ws, size_t ws_size,
                              hipStream_t stream) {
  const float* patch = (const float*)d_in[0];
  const float* lib   = (const float*)d_in[1];
  const float* meanp = (const float*)d_in[2];
  const float* stdp  = (const float*)d_in[3];
  float* out = (float*)d_out;

  char* ws = (char*)d_ws;
  size_t off = 0;
  auto alloc = [&](size_t bytes) -> void* {
    void* p = ws + off;
    off = (off + bytes + 255) & ~(size_t)255;
    return p;
  };
  bf16_t* pb      = (bf16_t*)alloc((size_t)N_PATCH * DIM * sizeof(bf16_t));
  bf16_t* lb      = (bf16_t*)alloc((size_t)N_LIB * DIM * sizeof(bf16_t));
  float* a2       = (float*)alloc(N_PATCH * sizeof(float));
  float* b2       = (float*)alloc(N_LIB * sizeof(float));
  unsigned long long* minpack = (unsigned long long*)alloc(N_PATCH * 8);
  float* min_val  = (float*)alloc(N_PATCH * sizeof(float));
  int*   min_idx  = (int*)alloc(N_PATCH * sizeof(int));
  float* wdist2   = (float*)alloc(N_LIB * sizeof(float));
  float* resized  = (float*)alloc(IMGSZ * IMGSZ * sizeof(float));
  Scal*  sc       = (Scal*)alloc(sizeof(Scal));

  init_kernel<<<(N_PATCH + 255) / 256, 256, 0, stream>>>(minpack, sc);
  prep_patch_kernel<<<N_PATCH, 192, 0, stream>>>(patch, meanp, stdp, pb, a2);
  prep_lib_kernel<<<N_LIB, 192, 0, stream>>>(lib, lb, b2);
  gemm_min_kernel<<<MT * NGRP, 256, 0, stream>>>(pb, lb, a2, b2, minpack);
  finalize_kernel<<<(N_PATCH + 255) / 256, 256, 0, stream>>>(minpack, min_val, min_idx, sc);
  collect_kernel<<<(N_PATCH + 255) / 256, 256, 0, stream>>>(min_val, sc);
  refine_kernel<<<dim3(64, 128), 256, 0, stream>>>(patch, lib, meanp, stdp, sc);
  pick_kernel<<<1, 64, 0, stream>>>(sc);
  wdist_kernel<<<N_LIB / 4, 256, 0, stream>>>(lib, sc, wdist2);
  top3_kernel<<<1, 256, 0, stream>>>(wdist2, patch, lib, meanp, stdp, sc, out);
  resize_kernel<<<(IMGSZ * IMGSZ + 255) / 256, 256, 0, stream>>>(min_val, resized);
  blur_kernel<<<(IMGSZ * IMGSZ + 255) / 256, 256, 0, stream>>>(resized, out + 1);
}